// Round 10
// baseline (213.504 us; speedup 1.0000x reference)
//
#include <hip/hip_runtime.h>

// Reference collapses: softmax over a size-1 key axis == 1.0, so
// out[bn,t,:] = padded[bn,t,:] + (masked_mean_t(padded[bn]) @ Wv + bv).
// q/k/rope/positions/sum_token are dead code.
//
// R14: sequential-pair pipelined single kernel.  Evidence ledger:
//  - single dispatch mandatory (R6/R11: multi-dispatch windows 80-86us
//    vs R8's 70).
//  - register residency / prefetch across phases: unwinnable (R5/R7/R8/
//    R13 -- compiler sinks or spills every time; R13's sched_barrier
//    attempt ROSE FETCH 54->96 MB and slowed 70->76).
//  - re-read AFTER matvec is L3-hot (R8 FETCH 54 MB); padded persists in
//    L3 across iterations, so HBM floor ~152 MB ~ 23us.
//  - R8's remaining 3x over floor = phase serialization (2 lockstep
//    rounds x [load 8us | matvec 4.3us | re-read 3.4 | store 8]).
// Structure: 256 blocks x 768 thr = EXACTLY 1 block/CU, no rounds.
// Block owns (bnA,bnB) serially: loadA+colsumA, loadB+colsumB, finalize
// both summaries, ONE shared Wv sweep for both matvecs (2 FMA/load;
// chip Wv L2 traffic 295->147 MB, per-CU matvec 8.6->4.3us), then
// re-readA+storeA, re-readB+storeB.  Loads are consumed immediately by
// colsum (no cross-phase register arrays -> nothing to sink); 3 barriers
// per PAIR (R8: 3 per bn).  nt stores for out.
// Prediction: kernel 52-60us, FETCH ~54-65 MB, WRITE ~98 MB.

#define DM 384
#define TT 128
#define C4 96          // DM / 4
#define NBLK 256       // 512 bn / 2 per block
#define NR  8          // row-groups (768 = 8 * 96)
#define RPT 16         // rows per thread per bn

typedef float f32x4 __attribute__((ext_vector_type(4)));

__device__ __forceinline__ void nt_store4(float4* p, const float4 v) {
    __builtin_nontemporal_store(*(const f32x4*)&v, (f32x4*)p);
}

__global__ __launch_bounds__(768, 4) void fused_seqpair(
    const float* __restrict__ padded,
    const int*   __restrict__ masks,
    const float* __restrict__ Wv,
    const float* __restrict__ bv,
    float*       __restrict__ out)
{
    const int bn0 = blockIdx.x << 1;     // block owns bn0, bn0+1
    const int t   = threadIdx.x;
    const int c   = t % C4;              // float4 column 0..95
    const int r   = t / C4;              // row-group 0..7

    __shared__ float  w_sh[2][TT];
    __shared__ float4 partA[NR][C4];     // 12 KB
    __shared__ float4 partB[NR][C4];     // 12 KB
    __shared__ float  summ[2][DM];       // 3 KB

    // both masks up front (one load for t<256)
    if (t < 2 * TT) w_sh[t >> 7][t & (TT - 1)] = (float)masks[bn0 * TT + t];

    const float4* __restrict__ pA = (const float4*)padded + (size_t)bn0 * TT * C4;
    const float4* __restrict__ pB = pA + TT * C4;

    __syncthreads();                     // B0: w_sh ready

    // ---- phase 1: loadA + masked colsumA (16 rows/thread, 4 accums) ----
    {
        float4 a0 = make_float4(0.f,0.f,0.f,0.f), a1 = a0, a2 = a0, a3 = a0;
        #pragma unroll
        for (int i = 0; i < 4; ++i) {
            const int  r0 = r + (4*i    ) * NR, r1 = r + (4*i + 1) * NR;
            const int  r2 = r + (4*i + 2) * NR, r3 = r + (4*i + 3) * NR;
            const float w0 = w_sh[0][r0], w1 = w_sh[0][r1];
            const float w2 = w_sh[0][r2], w3 = w_sh[0][r3];
            const float4 x0 = pA[r0 * C4 + c], x1 = pA[r1 * C4 + c];
            const float4 x2 = pA[r2 * C4 + c], x3 = pA[r3 * C4 + c];
            a0.x += x0.x*w0; a0.y += x0.y*w0; a0.z += x0.z*w0; a0.w += x0.w*w0;
            a1.x += x1.x*w1; a1.y += x1.y*w1; a1.z += x1.z*w1; a1.w += x1.w*w1;
            a2.x += x2.x*w2; a2.y += x2.y*w2; a2.z += x2.z*w2; a2.w += x2.w*w2;
            a3.x += x3.x*w3; a3.y += x3.y*w3; a3.z += x3.z*w3; a3.w += x3.w*w3;
        }
        a0.x += a1.x + a2.x + a3.x; a0.y += a1.y + a2.y + a3.y;
        a0.z += a1.z + a2.z + a3.z; a0.w += a1.w + a2.w + a3.w;
        partA[r][c] = a0;
    }

    // ---- phase 2: loadB + masked colsumB ----
    {
        float4 a0 = make_float4(0.f,0.f,0.f,0.f), a1 = a0, a2 = a0, a3 = a0;
        #pragma unroll
        for (int i = 0; i < 4; ++i) {
            const int  r0 = r + (4*i    ) * NR, r1 = r + (4*i + 1) * NR;
            const int  r2 = r + (4*i + 2) * NR, r3 = r + (4*i + 3) * NR;
            const float w0 = w_sh[1][r0], w1 = w_sh[1][r1];
            const float w2 = w_sh[1][r2], w3 = w_sh[1][r3];
            const float4 x0 = pB[r0 * C4 + c], x1 = pB[r1 * C4 + c];
            const float4 x2 = pB[r2 * C4 + c], x3 = pB[r3 * C4 + c];
            a0.x += x0.x*w0; a0.y += x0.y*w0; a0.z += x0.z*w0; a0.w += x0.w*w0;
            a1.x += x1.x*w1; a1.y += x1.y*w1; a1.z += x1.z*w1; a1.w += x1.w*w1;
            a2.x += x2.x*w2; a2.y += x2.y*w2; a2.z += x2.z*w2; a2.w += x2.w*w2;
            a3.x += x3.x*w3; a3.y += x3.y*w3; a3.z += x3.z*w3; a3.w += x3.w*w3;
        }
        a0.x += a1.x + a2.x + a3.x; a0.y += a1.y + a2.y + a3.y;
        a0.z += a1.z + a2.z + a3.z; a0.w += a1.w + a2.w + a3.w;
        partB[r][c] = a0;
    }
    __syncthreads();                     // B1: partials ready

    // ---- finalize both summaries in parallel (192 threads) ----
    if (t < 2 * C4) {
        const int s  = (t >= C4);
        const int cc = t - s * C4;
        float d0 = 0.f, d1 = 0.f, d2 = 0.f, d3 = 0.f;
        #pragma unroll
        for (int i = 0; i < 32; ++i) {
            d0 += w_sh[s][i];      d1 += w_sh[s][32 + i];
            d2 += w_sh[s][64 + i]; d3 += w_sh[s][96 + i];
        }
        const float inv = 1.0f / fmaxf((d0 + d1) + (d2 + d3), 1e-6f);

        const float4* part = s ? &partB[0][0] : &partA[0][0];
        float4 sm = part[cc];
        #pragma unroll
        for (int g = 1; g < NR; ++g) {
            const float4 p = part[g * C4 + cc];
            sm.x += p.x; sm.y += p.y; sm.z += p.z; sm.w += p.w;
        }
        sm.x *= inv; sm.y *= inv; sm.z *= inv; sm.w *= inv;
        ((float4*)summ[s])[cc] = sm;
    }
    __syncthreads();                     // B2: summaries ready

    // ---- shared matvec: one Wv sweep, both bn (2 FMA per load) ----
    {
        float4 aA = make_float4(0.f,0.f,0.f,0.f);
        float4 aB = make_float4(0.f,0.f,0.f,0.f);
        const float4* __restrict__ wv4 = (const float4*)Wv;
        const int e0 = r * (DM / NR);    // 48 Wv rows per row-group
        #pragma unroll 8
        for (int i = 0; i < DM / NR; ++i) {
            const int   e  = e0 + i;
            const float sA = summ[0][e];               // LDS broadcast
            const float sB = summ[1][e];
            const float4 w = wv4[(size_t)e * C4 + c];  // coalesced, L2-hot
            aA.x += sA*w.x; aA.y += sA*w.y; aA.z += sA*w.z; aA.w += sA*w.w;
            aB.x += sB*w.x; aB.y += sB*w.y; aB.z += sB*w.z; aB.w += sB*w.w;
        }
        partA[r][c] = aA;
        partB[r][c] = aB;
    }
    __syncthreads();                     // B3: matvec partials ready

    // ---- v-finalize per thread (LDS broadcast, no barrier) ----
    const float4 b = ((const float4*)bv)[c];
    float4 vA = b, vB = b;
    #pragma unroll
    for (int g = 0; g < NR; ++g) {
        const float4 qA = partA[g][c];
        const float4 qB = partB[g][c];
        vA.x += qA.x; vA.y += qA.y; vA.z += qA.z; vA.w += qA.w;
        vB.x += qB.x; vB.y += qB.y; vB.z += qB.z; vB.w += qB.w;
    }

    // ---- store A then B: re-read right after matvec = L3-hot (R8) ----
    float4* __restrict__ oA = (float4*)out + (size_t)bn0 * TT * C4;
    float4* __restrict__ oB = oA + TT * C4;
    #pragma unroll
    for (int i = 0; i < RPT; ++i) {
        const int idx = (r + i * NR) * C4 + c;
        float4 x = pA[idx];
        x.x += vA.x; x.y += vA.y; x.z += vA.z; x.w += vA.w;
        nt_store4(&oA[idx], x);
    }
    #pragma unroll
    for (int i = 0; i < RPT; ++i) {
        const int idx = (r + i * NR) * C4 + c;
        float4 x = pB[idx];
        x.x += vB.x; x.y += vB.y; x.z += vB.z; x.w += vB.w;
        nt_store4(&oB[idx], x);
    }
}

extern "C" void kernel_launch(void* const* d_in, const int* in_sizes, int n_in,
                              void* d_out, int out_size, void* d_ws, size_t ws_size,
                              hipStream_t stream) {
    const float* padded = (const float*)d_in[0];
    // d_in[1] sum_token, d_in[2] positions_3d, d_in[3..6] Wq/bq/Wk/bk: dead
    const float* Wv     = (const float*)d_in[7];
    const float* bv     = (const float*)d_in[8];
    const int*   masks  = (const int*)d_in[9];
    float* out = (float*)d_out;

    fused_seqpair<<<NBLK, 768, 0, stream>>>(padded, masks, Wv, bv, out);
}

// Round 11
// 206.703 us; speedup vs baseline: 1.0329x; 1.0329x over previous
//
#include <hip/hip_runtime.h>

// Reference collapses: softmax over a size-1 key axis == 1.0, so
// out[bn,t,:] = padded[bn,t,:] + (masked_mean_t(padded[bn]) @ Wv + bv).
// q/k/rope/positions/sum_token are dead code.
//
// R15 = R8 (best: 70us kernel / 205.2 total) + async LDS staging via
// global_load_lds.  Evidence ledger (10 rounds):
//  - R8 geometry (512 x 768thr, 1 bn/block) is the ONLY one with
//    FETCH=54 MB; every other structure re-fetches ~100 MB from HBM.
//  - multi-dispatch costs 10-15us launch overhead per extra dispatch.
//  - cross-block sync = disaster (R12 fences, 10x).
//  - register arrays across phases ALWAYS get sunk/spilled (R5/7/8/13).
// global_load_lds is side-effecting -> compiler cannot sink it.  R8's
// flat index p4[i*768 + t] is linear per wave = exactly the DMA's
// wave-uniform-base + lane*16 pattern.  Stage rounds 0..7 (96 KB) ONCE
// at kernel start; the staged copy feeds BOTH the colsum (phase 1) and
// the store-add (phase 4) -> first half of the tile is read from global
// exactly once instead of twice, phase-1 register pressure halves
// (x[8] all in flight), store-phase global re-read halves (rest L3-hot).
// Everything else byte-identical to R8 (nt stores, 4 barriers, matvec).
// Prediction: LDS ~112 KB, FETCH ~48-54 MB, kernel ~58-65us.

#define DM 384
#define TT 128
#define C4 96          // DM / 4
#define BN_TOT 512
#define NR  8          // row-groups (768 = 8 * 96)
#define NSTG 8         // rounds staged in LDS (rows 0..63):   96 KB
#define NREG 8         // rounds via registers (rows 64..127)

typedef float f32x4 __attribute__((ext_vector_type(4)));

__device__ __forceinline__ void nt_store4(float4* p, const float4 v) {
    __builtin_nontemporal_store(*(const f32x4*)&v, (f32x4*)p);
}

// async global->LDS DMA, 16B per lane; lds must be wave-uniform.
__device__ __forceinline__ void async_copy16(const void* g, void* lds) {
    __builtin_amdgcn_global_load_lds(
        (const __attribute__((address_space(1))) void*)g,
        (__attribute__((address_space(3))) void*)lds, 16, 0, 0);
}

__global__ __launch_bounds__(768, 4) void fused_ldsstage(
    const float* __restrict__ padded,
    const int*   __restrict__ masks,
    const float* __restrict__ Wv,
    const float* __restrict__ bv,
    float*       __restrict__ out)
{
    const int bn = blockIdx.x;
    const int t  = threadIdx.x;
    const int c  = t % C4;               // float4 column 0..95
    const int r  = t / C4;               // row-group 0..7

    __shared__ float4 stage[NSTG * 768]; // 96 KB: rows 0..63, linear layout
    __shared__ float  w_sh[TT];
    __shared__ float4 part_sh[NR][C4];   // 12 KB
    __shared__ float  summ[DM];

    // masks first so their waitcnt clears early
    int m = 0;
    if (t < TT) m = masks[bn * TT + t];

    const float4* __restrict__ p4 =
        (const float4*)padded + (size_t)bn * TT * C4;

    // ---- issue 8 async DMAs: rounds 0..7 -> LDS (side-effecting: ----
    // ---- the compiler CANNOT sink these, unlike register prefetch) ----
    const int wbase = t & ~63;           // wave-uniform LDS base index
    #pragma unroll
    for (int i = 0; i < NSTG; ++i)
        async_copy16(&p4[i * 768 + t], &stage[i * 768 + wbase]);

    // ---- register loads: rounds 8..15 (only 32 VGPRs -> all in flight) ----
    float4 x[NREG];
    #pragma unroll
    for (int i = 0; i < NREG; ++i) x[i] = p4[(NSTG + i) * 768 + t];

    if (t < TT) w_sh[t] = (float)m;
    __syncthreads();                     // drains DMA + loads; w_sh ready

    // ---- masked column partial sums; flat idx f = i*768+t -> row 8i+r ----
    float4 a0 = make_float4(0.f, 0.f, 0.f, 0.f);
    float4 a1 = make_float4(0.f, 0.f, 0.f, 0.f);
    #pragma unroll
    for (int i = 0; i < NSTG; ++i) {     // staged rounds: rows 8i + r
        const float  w = w_sh[8 * i + r];
        const float4 xv = stage[i * 768 + t];      // ds_read_b128
        a0.x += xv.x * w; a0.y += xv.y * w;
        a0.z += xv.z * w; a0.w += xv.w * w;
    }
    #pragma unroll
    for (int i = 0; i < NREG; ++i) {     // register rounds: rows 8(8+i) + r
        const float w = w_sh[8 * (NSTG + i) + r];
        a1.x += x[i].x * w; a1.y += x[i].y * w;
        a1.z += x[i].z * w; a1.w += x[i].w * w;
    }
    a0.x += a1.x; a0.y += a1.y; a0.z += a1.z; a0.w += a1.w;
    part_sh[r][c] = a0;
    __syncthreads();

    // ---- finalize summary (96 threads; denom via 4 parallel chains) ----
    if (t < C4) {
        float d0 = 0.f, d1 = 0.f, d2 = 0.f, d3 = 0.f;
        #pragma unroll
        for (int i = 0; i < 32; ++i) {
            d0 += w_sh[i];      d1 += w_sh[32 + i];
            d2 += w_sh[64 + i]; d3 += w_sh[96 + i];
        }
        const float inv = 1.0f / fmaxf((d0 + d1) + (d2 + d3), 1e-6f);

        float4 s = part_sh[0][t];
        #pragma unroll
        for (int g = 1; g < NR; ++g) {
            const float4 p = part_sh[g][t];
            s.x += p.x; s.y += p.y; s.z += p.z; s.w += p.w;
        }
        s.x *= inv; s.y *= inv; s.z *= inv; s.w *= inv;
        ((float4*)summ)[t] = s;
    }
    __syncthreads();

    // ---- matvec: row-group r covers Wv rows [r*48, r*48+48) ----
    float4 a = make_float4(0.f, 0.f, 0.f, 0.f);
    const float4* __restrict__ wv4 = (const float4*)Wv;
    const int e0 = r * (DM / NR);
    #pragma unroll 8
    for (int i = 0; i < DM / NR; ++i) {
        const int   e = e0 + i;
        const float s = summ[e];                    // LDS broadcast
        const float4 w = wv4[(size_t)e * C4 + c];   // coalesced, L2-hot
        a.x += s * w.x; a.y += s * w.y; a.z += s * w.z; a.w += s * w.w;
    }
    part_sh[r][c] = a;
    __syncthreads();

    // ---- v-finalize per thread (LDS broadcast, no extra barrier) ----
    float4 v = ((const float4*)bv)[c];
    #pragma unroll
    for (int g = 0; g < NR; ++g) {
        const float4 q = part_sh[g][c];
        v.x += q.x; v.y += q.y; v.z += q.z; v.w += q.w;
    }

    // ---- store: rounds 0..7 from LDS (no global re-read at all), ----
    // ---- rounds 8..15 re-read from global (L3-hot, R8-proven).    ----
    float4* __restrict__ o4 = (float4*)out + (size_t)bn * TT * C4;
    #pragma unroll
    for (int i = 0; i < NSTG; ++i) {
        float4 y = stage[i * 768 + t];
        y.x += v.x; y.y += v.y; y.z += v.z; y.w += v.w;
        nt_store4(&o4[i * 768 + t], y);
    }
    #pragma unroll
    for (int i = 0; i < NREG; ++i) {
        float4 y = p4[(NSTG + i) * 768 + t];
        y.x += v.x; y.y += v.y; y.z += v.z; y.w += v.w;
        nt_store4(&o4[(NSTG + i) * 768 + t], y);
    }
}

extern "C" void kernel_launch(void* const* d_in, const int* in_sizes, int n_in,
                              void* d_out, int out_size, void* d_ws, size_t ws_size,
                              hipStream_t stream) {
    const float* padded = (const float*)d_in[0];
    // d_in[1] sum_token, d_in[2] positions_3d, d_in[3..6] Wq/bq/Wk/bk: dead
    const float* Wv     = (const float*)d_in[7];
    const float* bv     = (const float*)d_in[8];
    const int*   masks  = (const int*)d_in[9];
    float* out = (float*)d_out;

    fused_ldsstage<<<BN_TOT, 768, 0, stream>>>(padded, masks, Wv, bv, out);
}